// Round 7
// baseline (255.539 us; speedup 1.0000x reference)
//
#include <hip/hip_runtime.h>

#define N_ENT   50000
#define N_ENT_P 50176
#define NDIM    256
#define BATCH   1024
#define MROWS   2048
#define BMT     256
#define BKT     64
#define NTILES  196
#define NSTRIP  32
#define SHIFT   30.0f

typedef __attribute__((ext_vector_type(8))) short short8;
typedef __attribute__((ext_vector_type(4))) float f32x4;

__device__ __forceinline__ unsigned short f2bf(float f) {
  unsigned int u = __float_as_uint(f);
  u += 0x7fffu + ((u >> 16) & 1u);          // RNE
  return (unsigned short)(u >> 16);
}

__device__ __forceinline__ void async16(const void* g, void* lds) {
  __builtin_amdgcn_global_load_lds(
      (const __attribute__((address_space(1))) unsigned int*)g,
      (__attribute__((address_space(3))) unsigned int*)lds,
      16, 0, 0);
}

// ---- K0 (fused): blocks [0,12544): ent_w f32 -> bf16 row-major Wb,
//      zero-pad rows [50000,50176); blocks [12544,12736): BN stats. ----
__global__ void k_prep(const float* __restrict__ ent_w,
                       unsigned short* __restrict__ Wb,
                       const int* __restrict__ facts,
                       const float* __restrict__ rel_w,
                       float* __restrict__ stats) {
  if (blockIdx.x < (N_ENT_P * 64) / 256) {
    int t = blockIdx.x * 256 + threadIdx.x;
    int row = t >> 6, c4 = (t & 63) << 2;
    ushort4 v;
    if (row < N_ENT) {
      float4 f = *(const float4*)(ent_w + row * NDIM + c4);
      v.x = f2bf(f.x); v.y = f2bf(f.y); v.z = f2bf(f.z); v.w = f2bf(f.w);
    } else {
      v.x = v.y = v.z = v.w = 0;
    }
    *(ushort4*)(Wb + row * NDIM + c4) = v;
  } else {
    int sb = blockIdx.x - (N_ENT_P * 64) / 256;  // [0,192)
    int seg = sb >> 6;                           // 0=h, 1=t, 2=r
    int d = threadIdx.x;
    const float* tab = (seg == 2) ? rel_w : ent_w;
    int r0 = (sb & 63) * 16;
    int idxs[16];
#pragma unroll
    for (int i = 0; i < 16; ++i) idxs[i] = facts[(r0 + i) * 3 + seg];
    float s = 0.f, s2 = 0.f;
#pragma unroll
    for (int i = 0; i < 16; ++i) {
      float v = tab[idxs[i] * NDIM + d];
      s += v; s2 += v * v;
    }
    atomicAdd(&stats[(seg * 2 + 0) * NDIM + d], s);
    atomicAdd(&stats[(seg * 2 + 1) * NDIM + d], s2);
  }
}

// ---- K2: BN apply + alpha bilinear -> head/tail vec (bf16) + exact label dots ----
__global__ void k_vectors(const int* __restrict__ facts, const int* __restrict__ arch,
                          const float* __restrict__ ent_w, const float* __restrict__ rel_w,
                          const float* __restrict__ bne_g, const float* __restrict__ bne_b,
                          const float* __restrict__ bnr_g, const float* __restrict__ bnr_b,
                          const float* __restrict__ stats,
                          unsigned short* __restrict__ HVb, float* __restrict__ zlab) {
  __shared__ float sh_he[256], sh_te[256], sh_re[256], sh_alpha[64], sh_red[16];
  int b = blockIdx.x, d = threadIdx.x;
  int h = facts[b * 3 + 0], t = facts[b * 3 + 1], r = facts[b * 3 + 2];
  const float inv = 1.0f / (float)BATCH;
  float mh = stats[0 * 256 + d] * inv, vh = stats[1 * 256 + d] * inv - mh * mh;
  float mt = stats[2 * 256 + d] * inv, vt = stats[3 * 256 + d] * inv - mt * mt;
  float mr = stats[4 * 256 + d] * inv, vr = stats[5 * 256 + d] * inv - mr * mr;
  float sch = rsqrtf(vh + 1e-5f) * bne_g[d], shh = bne_b[d] - mh * sch;
  float sct = rsqrtf(vt + 1e-5f) * bne_g[d], sht = bne_b[d] - mt * sct;
  float scr = rsqrtf(vr + 1e-5f) * bnr_g[d], shr = bnr_b[d] - mr * scr;
  sh_he[d] = ent_w[h * NDIM + d] * sch + shh;
  sh_te[d] = ent_w[t * NDIM + d] * sct + sht;
  sh_re[d] = rel_w[r * NDIM + d] * scr + shr;
  if (d < 64) {
    int a = arch[d];
    sh_alpha[d] = (a == 0) ? 0.f : ((a == 1) ? 1.f : -1.f);
  }
  __syncthreads();
  int k = d >> 6, l = d & 63;
  float hv = 0.f, tv = 0.f;
#pragma unroll
  for (int i = 0; i < 4; ++i) {
    float re_i = sh_re[i * 64 + l];
#pragma unroll
    for (int j = 0; j < 4; ++j) {
      hv += sh_alpha[i * 16 + j * 4 + k] * re_i * sh_te[j * 64 + l];
      tv += sh_alpha[i * 16 + k * 4 + j] * re_i * sh_he[j * 64 + l];
    }
  }
  HVb[b * NDIM + d] = f2bf(hv);
  HVb[(BATCH + b) * NDIM + d] = f2bf(tv);
  float ph = hv * ent_w[h * NDIM + d];
  float pt = tv * ent_w[t * NDIM + d];
  for (int m = 1; m < 64; m <<= 1) { ph += __shfl_xor(ph, m); pt += __shfl_xor(pt, m); }
  int wid = d >> 6;
  if ((d & 63) == 0) { sh_red[wid] = ph; sh_red[8 + wid] = pt; }
  __syncthreads();
  if (d == 0) {
    zlab[b] = sh_red[0] + sh_red[1] + sh_red[2] + sh_red[3];
    zlab[BATCH + b] = sh_red[8] + sh_red[9] + sh_red[10] + sh_red[11];
  }
}

// ---- K3: bf16 MFMA GEMM (2048 x 50176 x 256) + fused finalize.
//   256x256 tile, BK=64, 8 waves (2Mx4N, per-wave 128x64). LDS dbuf A+B,
//   counted vmcnt(8), dummy-tail. Each 64-K job = 4 phases of 16 MFMA with
//   CROSS-PHASE register pipelining: phase issues next phase's ds_reads
//   (sched_barrier-pinned), recycle point sits before P3 so P3's MFMA hides
//   the next job's first frag loads. Power sums accumulate in per-wave LDS
//   slabs (frees 64 VGPRs). launch_bounds(512,1): LDS forces 1 block/CU,
//   so the register cap is 256 — R6's (512,2) capped at 128 and spilled.
//   Last block (device-scope counter) computes the final loss in-kernel. ----
__global__ void __launch_bounds__(512, 1)
k_gemm(const unsigned short* __restrict__ HVb, const unsigned short* __restrict__ Wb,
       float* __restrict__ m1, float* __restrict__ m2,
       const float* __restrict__ zlab, unsigned int* __restrict__ cnt,
       float* __restrict__ out) {
  __shared__ __align__(16) unsigned short As[2][BMT * BKT];   // 2 x 32 KB
  __shared__ __align__(16) unsigned short Bs[2][BMT * BKT];   // 2 x 32 KB
  __shared__ float part[2][8][128];                           // 8 KB
  __shared__ float sred[8];
  __shared__ int slast;
  const int tid = threadIdx.x;
  const int lane = tid & 63, wid = tid >> 6;     // 8 waves
  const int L = blockIdx.x;                      // [0,256)
  const int s = (L >> 6) * 8 + (L & 7);          // strip [0,32), XCD-pinned
  const int bm = ((L >> 3) & 7) * BMT;           // m-block
  const int wm = (wid >> 2) * 128, wn = (wid & 3) * 64;
  const int q = lane >> 4, ln = lane & 15;
  const int ntmine = NTILES / NSTRIP + (s < (NTILES % NSTRIP) ? 1 : 0); // 6 or 7
  const int njobs = ntmine * 4;

  // zero power-sum slabs
  ((float*)part)[tid] = 0.f; ((float*)part)[512 + tid] = 0.f;
  ((float*)part)[1024 + tid] = 0.f; ((float*)part)[1536 + tid] = 0.f;

  // staging invariants (R6-verified): granule G = i*512+tid, row=G>>3, slot=G&7
  const int srow0 = tid >> 3;
  const int skg = (((tid & 7) ^ (srow0 & 7)) << 3);
  // frag read offsets, kh toggles byte bit 6 (XOR-linear swizzle)
  int aoffL[4], aoffH[4], boff0[4];
#pragma unroll
  for (int f = 0; f < 4; ++f) {
    aoffL[f] = (wm + f * 16 + ln) * 128 + ((q ^ (ln & 7)) << 4);
    aoffH[f] = (wm + (4 + f) * 16 + ln) * 128 + ((q ^ (ln & 7)) << 4);
    boff0[f] = (wn + f * 16 + ln) * 128 + ((q ^ (ln & 7)) << 4);
  }

  auto stage = [&](int j) {
    int jj = (j < njobs) ? j : j - 2;            // dummy tail, parity-safe
    int nt = jj >> 2, kt = jj & 3, buf = jj & 1;
    const unsigned short* Ag = HVb + (size_t)(bm + srow0) * NDIM + kt * 64 + skg;
    const unsigned short* Bg = Wb +
        (size_t)((s + nt * NSTRIP) * 256 + srow0) * NDIM + kt * 64 + skg;
    char* Ad = (char*)As[buf] + tid * 16;
    char* Bd = (char*)Bs[buf] + tid * 16;
#pragma unroll
    for (int i = 0; i < 4; ++i) {
      async16(Ag + i * (64 * NDIM), Ad + i * 8192);
      async16(Bg + i * (64 * NDIM), Bd + i * 8192);
    }
  };

#define MMA4(FA, FB, MO)                                                      \
  __builtin_amdgcn_s_setprio(1);                                              \
  _Pragma("unroll") for (int mi = 0; mi < 4; ++mi)                            \
      _Pragma("unroll") for (int ni = 0; ni < 4; ++ni)                        \
          acc[(MO) + mi][ni] = __builtin_amdgcn_mfma_f32_16x16x32_bf16(       \
              FA[mi], FB[ni], acc[(MO) + mi][ni], 0, 0, 0);                   \
  __builtin_amdgcn_s_setprio(0);

  short8 faA[4], faB[4], fbA[4], fbB[4];

  stage(0); stage(1);                            // 16 DMA inflight
  asm volatile("s_waitcnt vmcnt(8)" ::: "memory");   // job 0 landed
  __builtin_amdgcn_s_barrier();
#pragma unroll
  for (int f = 0; f < 4; ++f) faA[f] = *(const short8*)((const char*)As[0] + aoffL[f]);
#pragma unroll
  for (int f = 0; f < 4; ++f) fbA[f] = *(const short8*)((const char*)Bs[0] + boff0[f]);

  for (int nt = 0; nt < ntmine; ++nt) {
    f32x4 acc[8][4] = {};
#pragma unroll
    for (int kt = 0; kt < 4; ++kt) {
      const int p = kt & 1;
      const char* Ap = (const char*)As[p];
      const char* Bp = (const char*)Bs[p];
      const char* An = (const char*)As[p ^ 1];
      const char* Bn = (const char*)Bs[p ^ 1];
      // P0: issue faB(miH,kh0), fbB(kh1); MFMA faA x fbA -> acc[0..3]
#pragma unroll
      for (int f = 0; f < 4; ++f) faB[f] = *(const short8*)(Ap + aoffH[f]);
#pragma unroll
      for (int f = 0; f < 4; ++f) fbB[f] = *(const short8*)(Bp + (boff0[f] ^ 64));
      __builtin_amdgcn_sched_barrier(0);
      MMA4(faA, fbA, 0)
      // P1: issue faA(miL,kh1); MFMA faB x fbA -> acc[4..7]
#pragma unroll
      for (int f = 0; f < 4; ++f) faA[f] = *(const short8*)(Ap + (aoffL[f] ^ 64));
      __builtin_amdgcn_sched_barrier(0);
      MMA4(faB, fbA, 4)
      // P2: issue faB(miH,kh1); MFMA faA x fbB -> acc[0..3]
#pragma unroll
      for (int f = 0; f < 4; ++f) faB[f] = *(const short8*)(Ap + (aoffH[f] ^ 64));
      __builtin_amdgcn_sched_barrier(0);
      MMA4(faA, fbB, 0)
      // recycle buf p, prefetch next job's first frags from buf p^1
      asm volatile("s_waitcnt lgkmcnt(0)" ::: "memory");
      __builtin_amdgcn_s_barrier();
      stage(nt * 4 + kt + 2);
      asm volatile("s_waitcnt vmcnt(8)" ::: "memory");
      __builtin_amdgcn_s_barrier();
#pragma unroll
      for (int f = 0; f < 4; ++f) faA[f] = *(const short8*)(An + aoffL[f]);
#pragma unroll
      for (int f = 0; f < 4; ++f) fbA[f] = *(const short8*)(Bn + boff0[f]);
      __builtin_amdgcn_sched_barrier(0);
      // P3: MFMA faB x fbB -> acc[4..7] (covers the reads above)
      MMA4(faB, fbB, 4)
    }
    // fold tile into per-wave LDS power sums (pad cols ~ e^-30)
#pragma unroll
    for (int mi = 0; mi < 8; ++mi)
#pragma unroll
      for (int reg = 0; reg < 4; ++reg) {
        float a1 = 0.f, a2 = 0.f;
#pragma unroll
        for (int ni = 0; ni < 4; ++ni) {
          float e = __expf(acc[mi][ni][reg] - SHIFT);
          a1 += e; a2 += e * e;
        }
        for (int m = 1; m < 16; m <<= 1) { a1 += __shfl_xor(a1, m); a2 += __shfl_xor(a2, m); }
        if (ln == 0) {
          part[0][wid][mi * 16 + q * 4 + reg] += a1;
          part[1][wid][mi * 16 + q * 4 + reg] += a2;
        }
      }
  }
#undef MMA4
  asm volatile("s_waitcnt vmcnt(0)" ::: "memory");   // drain dummy DMA
  __syncthreads();
  {
    int kind = tid >> 8, rl = tid & 255;
    int w0 = (rl >> 7) * 4, rr = rl & 127;
    float v = part[kind][w0][rr] + part[kind][w0 + 1][rr] +
              part[kind][w0 + 2][rr] + part[kind][w0 + 3][rr];
    atomicAdd((kind ? m2 : m1) + bm + rl, v);
  }
  // ---- fused finalize: last block assembles the loss ----
  __threadfence();
  if (tid == 0) slast = (atomicAdd(cnt, 1u) + 1u == 256u) ? 1 : 0;
  __syncthreads();
  if (slast) {
    __threadfence();
    float local = 0.f;
    for (int r = tid; r < MROWS; r += 512) {
      float M1 = __hip_atomic_load(&m1[r], __ATOMIC_RELAXED, __HIP_MEMORY_SCOPE_AGENT);
      float M2 = __hip_atomic_load(&m2[r], __ATOMIC_RELAXED, __HIP_MEMORY_SCOPE_AGENT);
      float lse = SHIFT + logf(M1);
      float zl = zlab[r];
      float lp = fmaxf(zl - lse, -100.f);
      float pl = __expf(zl - lse);
      float l1m = fmaxf(log1pf(-pl), -100.f);
      float iM1 = 1.f / M1;
      float r2 = M2 * iM1 * iM1;
      float series = -(1.f + 0.5f * r2);     // sum_e log1p(-p_e), p sums to 1
      local += lp - l1m + series;
    }
    for (int m = 1; m < 64; m <<= 1) local += __shfl_xor(local, m);
    if ((tid & 63) == 0) sred[tid >> 6] = local;
    __syncthreads();
    if (tid == 0) {
      float ssum = 0.f;
      for (int i = 0; i < 8; ++i) ssum += sred[i];
      out[0] = -ssum / ((float)BATCH * (float)N_ENT);
    }
  }
}

extern "C" void kernel_launch(void* const* d_in, const int* in_sizes, int n_in,
                              void* d_out, int out_size, void* d_ws, size_t ws_size,
                              hipStream_t stream) {
  const int* facts = (const int*)d_in[0];
  const int* arch = (const int*)d_in[1];
  const float* ent_w = (const float*)d_in[2];
  const float* rel_w = (const float*)d_in[3];
  const float* bne_g = (const float*)d_in[4];
  const float* bne_b = (const float*)d_in[5];
  const float* bnr_g = (const float*)d_in[6];
  const float* bnr_b = (const float*)d_in[7];
  char* ws = (char*)d_ws;
  // layout: [stats 6144][m1 8192][m2 8192][cnt 16][pad][zlab@24576 8192]
  //         [HVb@32768 1MB][Wb 25.7MB]
  float* stats = (float*)ws;
  float* m1 = (float*)(ws + 6144);
  float* m2 = (float*)(ws + 14336);
  unsigned int* cnt = (unsigned int*)(ws + 22528);
  float* zlab = (float*)(ws + 24576);
  unsigned short* HVb = (unsigned short*)(ws + 32768);
  unsigned short* Wb = (unsigned short*)(ws + 32768 + 1048576);

  hipMemsetAsync(ws, 0, 22544, stream);  // stats + m1 + m2 + cnt
  k_prep<<<dim3((N_ENT_P * 64) / 256 + 192), dim3(256), 0, stream>>>(
      ent_w, Wb, facts, rel_w, stats);
  k_vectors<<<dim3(BATCH), dim3(256), 0, stream>>>(facts, arch, ent_w, rel_w,
                                                   bne_g, bne_b, bnr_g, bnr_b,
                                                   stats, HVb, zlab);
  k_gemm<<<dim3(256), dim3(512), 0, stream>>>(HVb, Wb, m1, m2, zlab, cnt,
                                              (float*)d_out);
}

// Round 10
// 180.337 us; speedup vs baseline: 1.4170x; 1.4170x over previous
//
#include <hip/hip_runtime.h>

#define N_ENT   50000
#define N_ENT_P 50176
#define NDIM    256
#define BATCH   1024
#define MROWS   2048
#define AM      64
#define NTILES  196
#define NSTRIP  32
#define SHIFT   30.0f

typedef __attribute__((ext_vector_type(8))) short short8;
typedef __attribute__((ext_vector_type(4))) float f32x4;

__device__ __forceinline__ unsigned short f2bf(float f) {
  unsigned int u = __float_as_uint(f);
  u += 0x7fffu + ((u >> 16) & 1u);          // RNE
  return (unsigned short)(u >> 16);
}

__device__ __forceinline__ void async16(const void* g, void* lds) {
  __builtin_amdgcn_global_load_lds(
      (const __attribute__((address_space(1))) unsigned int*)g,
      (__attribute__((address_space(3))) unsigned int*)lds,
      16, 0, 0);
}

// ---- K0 (fused): blocks [0,3136): ent_w f32 -> bf16 MFMA-FRAGMENT layout
//      (granule (nt,kc,lane)=B[nt*16+ln][kc*32+q*8..+7], 1024 B per wave-frag);
//      blocks [3136,3328): BN stats (sum,sumsq), 16 rows/block.
//      (Ran verified in R5.) ----
__global__ void k_prep(const float* __restrict__ ent_w,
                       unsigned short* __restrict__ Wb,
                       const int* __restrict__ facts,
                       const float* __restrict__ rel_w,
                       float* __restrict__ stats) {
  if (blockIdx.x < 3136) {
    int nt = blockIdx.x;
    int tid = threadIdx.x;                    // 256
#pragma unroll
    for (int h = 0; h < 2; ++h) {
      int g = h * 256 + tid;                  // granule in [0,512)
      int kc = g >> 6, lane = g & 63;
      int qq = lane >> 4, lnn = lane & 15;
      int row = nt * 16 + lnn, col = kc * 32 + qq * 8;
      short8 v;
      if (row < N_ENT) {
        const float* s = ent_w + row * NDIM + col;
        float4 f0 = *(const float4*)s, f1 = *(const float4*)(s + 4);
        v[0] = (short)f2bf(f0.x); v[1] = (short)f2bf(f0.y);
        v[2] = (short)f2bf(f0.z); v[3] = (short)f2bf(f0.w);
        v[4] = (short)f2bf(f1.x); v[5] = (short)f2bf(f1.y);
        v[6] = (short)f2bf(f1.z); v[7] = (short)f2bf(f1.w);
      } else {
        v = (short8)(0);
      }
      *(short8*)(Wb + nt * 4096 + g * 8) = v;
    }
  } else {
    int sb = blockIdx.x - 3136;               // [0,192)
    int seg = sb >> 6;                        // 0=h, 1=t, 2=r
    int d = threadIdx.x;
    const float* tab = (seg == 2) ? rel_w : ent_w;
    int r0 = (sb & 63) * 16;
    int idxs[16];
#pragma unroll
    for (int i = 0; i < 16; ++i) idxs[i] = facts[(r0 + i) * 3 + seg];
    float s = 0.f, s2 = 0.f;
#pragma unroll
    for (int i = 0; i < 16; ++i) {
      float v = tab[idxs[i] * NDIM + d];
      s += v; s2 += v * v;
    }
    atomicAdd(&stats[(seg * 2 + 0) * NDIM + d], s);
    atomicAdd(&stats[(seg * 2 + 1) * NDIM + d], s2);
  }
}

// ---- K2: BN apply + alpha bilinear -> head/tail vec (bf16) + exact label dots ----
__global__ void k_vectors(const int* __restrict__ facts, const int* __restrict__ arch,
                          const float* __restrict__ ent_w, const float* __restrict__ rel_w,
                          const float* __restrict__ bne_g, const float* __restrict__ bne_b,
                          const float* __restrict__ bnr_g, const float* __restrict__ bnr_b,
                          const float* __restrict__ stats,
                          unsigned short* __restrict__ HVb, float* __restrict__ zlab) {
  __shared__ float sh_he[256], sh_te[256], sh_re[256], sh_alpha[64], sh_red[16];
  int b = blockIdx.x, d = threadIdx.x;
  int h = facts[b * 3 + 0], t = facts[b * 3 + 1], r = facts[b * 3 + 2];
  const float inv = 1.0f / (float)BATCH;
  float mh = stats[0 * 256 + d] * inv, vh = stats[1 * 256 + d] * inv - mh * mh;
  float mt = stats[2 * 256 + d] * inv, vt = stats[3 * 256 + d] * inv - mt * mt;
  float mr = stats[4 * 256 + d] * inv, vr = stats[5 * 256 + d] * inv - mr * mr;
  float sch = rsqrtf(vh + 1e-5f) * bne_g[d], shh = bne_b[d] - mh * sch;
  float sct = rsqrtf(vt + 1e-5f) * bne_g[d], sht = bne_b[d] - mt * sct;
  float scr = rsqrtf(vr + 1e-5f) * bnr_g[d], shr = bnr_b[d] - mr * scr;
  sh_he[d] = ent_w[h * NDIM + d] * sch + shh;
  sh_te[d] = ent_w[t * NDIM + d] * sct + sht;
  sh_re[d] = rel_w[r * NDIM + d] * scr + shr;
  if (d < 64) {
    int a = arch[d];
    sh_alpha[d] = (a == 0) ? 0.f : ((a == 1) ? 1.f : -1.f);
  }
  __syncthreads();
  int k = d >> 6, l = d & 63;
  float hv = 0.f, tv = 0.f;
#pragma unroll
  for (int i = 0; i < 4; ++i) {
    float re_i = sh_re[i * 64 + l];
#pragma unroll
    for (int j = 0; j < 4; ++j) {
      hv += sh_alpha[i * 16 + j * 4 + k] * re_i * sh_te[j * 64 + l];
      tv += sh_alpha[i * 16 + k * 4 + j] * re_i * sh_he[j * 64 + l];
    }
  }
  HVb[b * NDIM + d] = f2bf(hv);
  HVb[(BATCH + b) * NDIM + d] = f2bf(tv);
  float ph = hv * ent_w[h * NDIM + d];
  float pt = tv * ent_w[t * NDIM + d];
  for (int m = 1; m < 64; m <<= 1) { ph += __shfl_xor(ph, m); pt += __shfl_xor(pt, m); }
  int wid = d >> 6;
  if ((d & 63) == 0) { sh_red[wid] = ph; sh_red[8 + wid] = pt; }
  __syncthreads();
  if (d == 0) {
    zlab[b] = sh_red[0] + sh_red[1] + sh_red[2] + sh_red[3];
    zlab[BATCH + b] = sh_red[8] + sh_red[9] + sh_red[10] + sh_red[11];
  }
}

// ---- K3: bf16 MFMA GEMM (2048 x 50176 x 256).
//   R4's kernel body VERBATIM (68 us, 128 VGPR, no spill, MfmaUtil 31.5%):
//   A (64x256) staged once to LDS (32 KB swizzled), B direct global->VGPR
//   from fragment-laid Wb (1024 B coalesced), double-buffered, compiler-
//   counted waits, no loop barriers. ONLY change vs R4: NSTRIP 16->32 so
//   grid = 1024 = 4 blocks/CU (4 waves/SIMD) — R4 was grid-starved at 2.
//   launch_bounds stays (256,2): no register squeeze. No fused finalize
//   (suspected in the R8/R9 container deaths — reverted to own dispatch). ----
__global__ void __launch_bounds__(256, 2)
k_gemm(const unsigned short* __restrict__ HVb, const unsigned short* __restrict__ Wb,
       float* __restrict__ m1, float* __restrict__ m2) {
  __shared__ __align__(16) unsigned short As[4 * AM * 64];   // 32 KB, 4 chunks
  const int tid = threadIdx.x;
  const int lane = tid & 63, wn4 = tid >> 6;     // 4 waves = 4 n-quarters
  const int L = blockIdx.x;                      // [0,1024)
  const int xcd = L & 7, rr = L >> 3;            // rr in [0,128)
  // heavy strips 0-3 (196%32=4) land on 4 DIFFERENT XCDs
  const int strip = (rr >> 5) * 8 + xcd;         // [0,32), XCD-pinned
  const int bm = (rr & 31) * AM;
  const int q = lane >> 4, ln = lane & 15;

  const int ntmine = NTILES / NSTRIP + (strip < (NTILES % NSTRIP) ? 1 : 0); // 6 or 7

  // ---- stage A strip once: 4 chunks x 512 granules ----
#pragma unroll
  for (int c = 0; c < 4; ++c)
#pragma unroll
    for (int i = 0; i < 2; ++i) {
      int G = i * 256 + tid;                     // [0,512)
      int row = G >> 3, slot = G & 7;
      int kg = slot ^ (row & 7);
      async16(HVb + (bm + row) * NDIM + c * 64 + kg * 8,
              (char*)As + c * 8192 + G * 16);
    }

  // A frag read byte-offsets (swizzled); chunk-half parity toggles bit 6
  int aoffq[4];
#pragma unroll
  for (int mi = 0; mi < 4; ++mi) {
    int row = mi * 16 + ln;
    aoffq[mi] = row * 128 + ((q ^ (row & 7)) << 4);
  }

  __syncthreads();                               // A staged (drains the 8 DMA ops)

  // B fragment pointer for this wave's 4 n-subtiles (shorts)
  const unsigned short* bp =
      Wb + (size_t)strip * 65536 + (size_t)wn4 * 16384 + (size_t)lane * 8;

  short8 fa0[4], fa1[4], fb0[4], fb1[4];
  float ps1[4][4] = {}, ps2[4][4] = {};

#define RDA(CN, FA)                                                           \
  {                                                                           \
    const char* Ac = (const char*)As + ((((CN)) & 7) >> 1) * 8192;            \
    const int axor = (((CN)) & 1) << 6;                                       \
    _Pragma("unroll") for (int mi = 0; mi < 4; ++mi)                          \
        FA[mi] = *(const short8*)(Ac + (aoffq[mi] ^ axor));                   \
  }
#define RDB(BP, CN, FB)                                                       \
  _Pragma("unroll") for (int ni = 0; ni < 4; ++ni)                            \
      FB[ni] = *(const short8*)((BP) + (CN) * 512 + ni * 4096);
#define MM(FA, FB)                                                            \
  {                                                                           \
    __builtin_amdgcn_s_setprio(1);                                            \
    _Pragma("unroll") for (int mi = 0; mi < 4; ++mi)                          \
        _Pragma("unroll") for (int ni = 0; ni < 4; ++ni)                      \
            acc[mi][ni] = __builtin_amdgcn_mfma_f32_16x16x32_bf16(            \
                FA[mi], FB[ni], acc[mi][ni], 0, 0, 0);                        \
    __builtin_amdgcn_s_setprio(0);                                            \
  }

  RDA(0, fa0); RDB(bp, 0, fb0);                  // prologue frags
  for (int ti = 0; ti < ntmine; ++ti) {
    const unsigned short* bpn =
        (ti + 1 < ntmine) ? bp + (size_t)NSTRIP * 65536 : bp;   // clamp = dummy
    f32x4 acc[4][4] = {};
    RDA(1, fa1); RDB(bp, 1, fb1);  MM(fa0, fb0);
    RDA(2, fa0); RDB(bp, 2, fb0);  MM(fa1, fb1);
    RDA(3, fa1); RDB(bp, 3, fb1);  MM(fa0, fb0);
    RDA(4, fa0); RDB(bp, 4, fb0);  MM(fa1, fb1);
    RDA(5, fa1); RDB(bp, 5, fb1);  MM(fa0, fb0);
    RDA(6, fa0); RDB(bp, 6, fb0);  MM(fa1, fb1);
    RDA(7, fa1); RDB(bp, 7, fb1);  MM(fa0, fb0);
    RDA(0, fa0); RDB(bpn, 0, fb0); MM(fa1, fb1); // preload next tile's phase 0
    bp = bpn;
    // consume acc into register power sums (pad cols contribute e^-30 ~ 0);
    // overlaps the next tile's phase-0 load latency
#pragma unroll
    for (int mi = 0; mi < 4; ++mi)
#pragma unroll
      for (int reg = 0; reg < 4; ++reg) {
        float s1 = 0.f, s2 = 0.f;
#pragma unroll
        for (int ni = 0; ni < 4; ++ni) {
          float e1 = __expf(acc[mi][ni][reg] - SHIFT);
          s1 += e1; s2 += e1 * e1;
        }
        ps1[mi][reg] += s1;
        ps2[mi][reg] += s2;
      }
  }
#undef MM
#undef RDB
#undef RDA

  // one reduce + atomic round per block
#pragma unroll
  for (int mi = 0; mi < 4; ++mi)
#pragma unroll
    for (int reg = 0; reg < 4; ++reg) {
      float s1 = ps1[mi][reg], s2 = ps2[mi][reg];
      for (int m = 1; m < 16; m <<= 1) { s1 += __shfl_xor(s1, m); s2 += __shfl_xor(s2, m); }
      if (ln == 0) {
        int grow = bm + mi * 16 + q * 4 + reg;
        atomicAdd(&m1[grow], s1);
        atomicAdd(&m2[grow], s2);
      }
    }
}

// ---- K4: per-row loss assembly + scalar reduce ----
__global__ void k_finalize(const float* __restrict__ m1, const float* __restrict__ m2,
                           const float* __restrict__ zlab, float* __restrict__ out) {
  __shared__ float red[16];
  int tid = threadIdx.x;  // 1024 threads
  float local = 0.f;
  for (int r = tid; r < MROWS; r += 1024) {
    float M1 = m1[r];
    float lse = SHIFT + logf(M1);
    float zl = zlab[r];
    float lp = fmaxf(zl - lse, -100.f);                 // log p_label
    float pl = __expf(zl - lse);
    float l1m = fmaxf(log1pf(-pl), -100.f);             // log(1-p_label)
    float iM1 = 1.f / M1;
    float r2 = m2[r] * iM1 * iM1;
    // sum_e log1p(-p_e) = -(1 + sum p^2/2 + O(p^3)); sum p == 1 exactly
    float series = -(1.f + 0.5f * r2);
    local += lp - l1m + series;
  }
  for (int m = 1; m < 64; m <<= 1) local += __shfl_xor(local, m);
  if ((tid & 63) == 0) red[tid >> 6] = local;
  __syncthreads();
  if (tid == 0) {
    float s = 0.f;
    for (int i = 0; i < 16; ++i) s += red[i];
    out[0] = -s / ((float)BATCH * (float)N_ENT);
  }
}

extern "C" void kernel_launch(void* const* d_in, const int* in_sizes, int n_in,
                              void* d_out, int out_size, void* d_ws, size_t ws_size,
                              hipStream_t stream) {
  const int* facts = (const int*)d_in[0];
  const int* arch = (const int*)d_in[1];
  const float* ent_w = (const float*)d_in[2];
  const float* rel_w = (const float*)d_in[3];
  const float* bne_g = (const float*)d_in[4];
  const float* bne_b = (const float*)d_in[5];
  const float* bnr_g = (const float*)d_in[6];
  const float* bnr_b = (const float*)d_in[7];
  char* ws = (char*)d_ws;
  // layout: [stats 6144][m1 8192][m2 8192][zlab 8192][HVb 1MB][Wb 25.7MB]
  float* stats = (float*)ws;
  float* m1 = (float*)(ws + 6144);
  float* m2 = (float*)(ws + 14336);
  float* zlab = (float*)(ws + 22528);
  unsigned short* HVb = (unsigned short*)(ws + 30720);
  unsigned short* Wb = (unsigned short*)(ws + 30720 + 1048576);

  hipMemsetAsync(ws, 0, 22528, stream);  // stats + m1 + m2
  k_prep<<<dim3(3328), dim3(256), 0, stream>>>(ent_w, Wb, facts, rel_w, stats);
  k_vectors<<<dim3(BATCH), dim3(256), 0, stream>>>(facts, arch, ent_w, rel_w,
                                                   bne_g, bne_b, bnr_g, bnr_b,
                                                   stats, HVb, zlab);
  k_gemm<<<dim3(1024), dim3(256), 0, stream>>>(HVb, Wb, m1, m2);
  k_finalize<<<dim3(1), dim3(1024), 0, stream>>>(m1, m2, zlab, (float*)d_out);
}